// Round 5
// baseline (89.880 us; speedup 1.0000x reference)
//
#include <hip/hip_runtime.h>
#include <math.h>

// IntraVolume_Attention collapses algebraically:
//   scores[b,v,f,g] = c * x[b,v,f] * x[b,v,g],  c = dot(w_q,w_k)/sqrt(128)
//   out[b,v,d] = w_v[d] * mean_f( softmax_weighted_mean_g(x) with logits c*x_f*x_g )
//
// ROUND 5 = MEASUREMENT PROBE. R2/R3/R4 (same 67M exps, wildly different
// structure/occupancy) all land at dur ~68-70 us. Two hypotheses:
//   A: kernel ~4 us, harness floor ~65 us  -> done, it's all re-poison fills.
//   B: kernel ~25 us (exp-proportional throughput bound), floor ~44 us.
// dur = floor + k is one equation, two unknowns. This round launches the
// IDENTICAL p1 kernel 3x (extra two write unused scratch) -> k = (dur-69.8)/2.

#if __has_builtin(__builtin_amdgcn_exp2f)
#define EXP2(x) __builtin_amdgcn_exp2f(x)   // raw v_exp_f32
#else
#define EXP2(x) exp2f(x)
#endif

#define F_DIM 512

__global__ __launch_bounds__(512) void intravol_p1(
    const float* __restrict__ x,    // [256, 512]
    const float* __restrict__ wq,   // [128]
    const float* __restrict__ wk,   // [128]
    float* __restrict__ part)       // [1024] partial sums (one per block)
{
    __shared__ __align__(16) float xs[F_DIM];
    __shared__ float pden[8][128];  // [g-slice][f-local]
    __shared__ float pnum[8][128];
    __shared__ float wmax[8], wmin[8], wsum[2];
    __shared__ float s_c, s_xmax, s_xmin;

    const int tid  = threadIdx.x;
    const int lane = tid & 63;
    const int wave = tid >> 6;
    const int row  = blockIdx.x >> 2;   // (b,v) row
    const int prt  = blockIdx.x & 3;    // which 128-f quarter

    // Stage full row; reduce max/min across all 8 waves.
    const float xv = x[row * F_DIM + tid];
    xs[tid] = xv;
    float mx = xv, mn = xv;
    for (int o = 32; o > 0; o >>= 1) {
        mx = fmaxf(mx, __shfl_down(mx, o));
        mn = fminf(mn, __shfl_down(mn, o));
    }
    if (lane == 0) { wmax[wave] = mx; wmin[wave] = mn; }
    __syncthreads();
    if (tid == 0) {
        float M = wmax[0], m_ = wmin[0];
        #pragma unroll
        for (int i = 1; i < 8; ++i) { M = fmaxf(M, wmax[i]); m_ = fminf(m_, wmin[i]); }
        s_xmax = M; s_xmin = m_;
    } else if (wave == 1) {             // concurrently: c = dot(wq,wk)/sqrt(128)
        float d = wq[lane] * wk[lane] + wq[lane + 64] * wk[lane + 64];
        for (int o = 32; o > 0; o >>= 1) d += __shfl_down(d, o);
        if (lane == 0) s_c = d * 0.08838834764831845f;
    }
    __syncthreads();

    // Thread = (f-pair, 64-g slice). Slice uniform per wave -> LDS broadcast.
    const float LOG2E = 1.4426950408889634f;
    const int sl = tid >> 6;            // == wave, g-slice
    const int fl = (tid & 63) << 1;     // local f (0..126, step 2)
    const int f  = (prt << 7) + fl;

    const float a0 = s_c * xs[f]     * LOG2E;
    const float a1 = s_c * xs[f + 1] * LOG2E;
    const float b0 = -((a0 >= 0.0f) ? a0 * s_xmax : a0 * s_xmin);
    const float b1 = -((a1 >= 0.0f) ? a1 * s_xmax : a1 * s_xmin);

    float d0 = 0.0f, d1 = 0.0f, n0 = 0.0f, n1 = 0.0f;
    const float4* xs4 = (const float4*)&xs[sl << 6];
    #pragma unroll
    for (int i = 0; i < 16; ++i) {      // 16 broadcast ds_read_b128
        const float4 v = xs4[i];
        const float xg_[4] = { v.x, v.y, v.z, v.w };
        #pragma unroll
        for (int j = 0; j < 4; ++j) {
            const float xg = xg_[j];
            const float e0 = EXP2(fmaf(a0, xg, b0));
            const float e1 = EXP2(fmaf(a1, xg, b1));
            d0 += e0; n0 = fmaf(e0, xg, n0);
            d1 += e1; n1 = fmaf(e1, xg, n1);
        }
    }
    pden[sl][fl] = d0; pden[sl][fl + 1] = d1;
    pnum[sl][fl] = n0; pnum[sl][fl + 1] = n1;
    __syncthreads();

    // Combine 8 slices per f, s_f = num/den, sum over the 128 local f's.
    float sf = 0.0f;
    if (tid < 128) {
        float D = 0.0f, N = 0.0f;
        #pragma unroll
        for (int s = 0; s < 8; ++s) { D += pden[s][tid]; N += pnum[s][tid]; }
        sf = N / D;
    }
    float t = sf;
    for (int o = 32; o > 0; o >>= 1) t += __shfl_down(t, o);
    if (lane == 0 && wave < 2) wsum[wave] = t;
    __syncthreads();
    if (tid == 0) part[blockIdx.x] = wsum[0] + wsum[1];
}

__global__ __launch_bounds__(128) void intravol_p2(
    const float* __restrict__ part,  // [1024]
    const float* __restrict__ wv,    // [128]
    float* __restrict__ out)         // [256, 128]
{
    const int r = blockIdx.x;
    const int t = threadIdx.x;
    const float S = part[4 * r] + part[4 * r + 1] + part[4 * r + 2] + part[4 * r + 3];
    out[r * 128 + t] = S * (1.0f / (float)F_DIM) * wv[t];
}

extern "C" void kernel_launch(void* const* d_in, const int* in_sizes, int n_in,
                              void* d_out, int out_size, void* d_ws, size_t ws_size,
                              hipStream_t stream) {
    const float* x  = (const float*)d_in[0];  // [8,32,512]
    const float* wq = (const float*)d_in[1];  // [1,128]
    const float* wk = (const float*)d_in[2];  // [1,128]
    const float* wv = (const float*)d_in[3];  // [1,128]
    float* out   = (float*)d_out;             // [8,32,128]
    float* part  = (float*)d_ws;              // [1024] real partials
    float* junk1 = (float*)d_ws + 1024;       // probe sinks (never read)
    float* junk2 = (float*)d_ws + 2048;

    // PROBE: p1 three times (identical work). k = (dur - dur_R4) / 2.
    intravol_p1<<<1024, 512, 0, stream>>>(x, wq, wk, junk1);
    intravol_p1<<<1024, 512, 0, stream>>>(x, wq, wk, junk2);
    intravol_p1<<<1024, 512, 0, stream>>>(x, wq, wk, part);
    intravol_p2<<<256, 128, 0, stream>>>(part, wv, out);
}

// Round 6
// 66.615 us; speedup vs baseline: 1.3493x; 1.3493x over previous
//
#include <hip/hip_runtime.h>
#include <math.h>

// IntraVolume_Attention collapses algebraically:
//   scores[b,v,f,g] = c * x[b,v,f] * x[b,v,g],  c = dot(w_q,w_k)/sqrt(128)
//   out[b,v,d] = w_v[d] * mean_f( softmax_weighted_mean_g(x) with logits c*x_f*x_g )
//
// Measured model (R1-R5): harness floor ~58-60 us (268 MB d_ws re-poison at
// HBM peak, outside kernel control); kernel is trans-pipe bound at ~22
// cyc/wave-element = 3 VALU x 2cyc + v_exp_f32 x 16cyc on a single-issue
// vector pipe. R6: single kernel (no p2 launch) + f-pair packed f32 VALU
// (v_pk_fma/v_pk_add) to cut per-2-element issue cost 44 -> 38 cyc.

#if __has_builtin(__builtin_amdgcn_exp2f)
#define EXP2(x) __builtin_amdgcn_exp2f(x)   // raw v_exp_f32
#else
#define EXP2(x) exp2f(x)
#endif

typedef float v2f __attribute__((ext_vector_type(2)));

#define F_DIM 512

__global__ __launch_bounds__(1024) void intravol_attn(
    const float* __restrict__ x,    // [256, 512]
    const float* __restrict__ wq,   // [128]
    const float* __restrict__ wk,   // [128]
    const float* __restrict__ wv,   // [128]
    float* __restrict__ out)        // [256, 128]
{
    __shared__ __align__(16) float xs[F_DIM];
    __shared__ __align__(8) float pden[4][F_DIM];  // [g-slice][f]
    __shared__ __align__(8) float pnum[4][F_DIM];
    __shared__ float wmax[8], wmin[8], wsum[8];
    __shared__ float s_c, s_xmax, s_xmin;

    const int tid  = threadIdx.x;
    const int lane = tid & 63;
    const int wave = tid >> 6;
    const int row  = blockIdx.x;

    // Stage the row (threads 0..511); waves 0..7 reduce max/min, wave 8
    // concurrently computes c = dot(wq,wk)/sqrt(128).
    float xv = 0.0f;
    if (tid < F_DIM) { xv = x[row * F_DIM + tid]; xs[tid] = xv; }
    if (wave < 8) {
        float mx = xv, mn = xv;
        for (int o = 32; o > 0; o >>= 1) {
            mx = fmaxf(mx, __shfl_down(mx, o));
            mn = fminf(mn, __shfl_down(mn, o));
        }
        if (lane == 0) { wmax[wave] = mx; wmin[wave] = mn; }
    } else if (wave == 8) {
        float d = wq[lane] * wk[lane] + wq[lane + 64] * wk[lane + 64];
        for (int o = 32; o > 0; o >>= 1) d += __shfl_down(d, o);
        if (lane == 0) s_c = d * 0.08838834764831845f;
    }
    __syncthreads();
    if (tid == 0) {
        float M = wmax[0], m_ = wmin[0];
        #pragma unroll
        for (int i = 1; i < 8; ++i) { M = fmaxf(M, wmax[i]); m_ = fminf(m_, wmin[i]); }
        s_xmax = M; s_xmin = m_;
    }
    __syncthreads();

    // Thread = (f-pair, 128-g slice). Slice uniform per wave -> LDS broadcast.
    const float LOG2E = 1.4426950408889634f;
    const int f0 = (tid & 255) << 1;    // even f
    const int sl = tid >> 8;            // g-slice 0..3

    const float a0 = s_c * xs[f0]     * LOG2E;
    const float a1 = s_c * xs[f0 + 1] * LOG2E;
    v2f a2  = { a0, a1 };
    v2f bb  = { -((a0 >= 0.0f) ? a0 * s_xmax : a0 * s_xmin),
                -((a1 >= 0.0f) ? a1 * s_xmax : a1 * s_xmin) };
    v2f den = { 0.0f, 0.0f };
    v2f num = { 0.0f, 0.0f };

    const float4* xs4 = (const float4*)&xs[sl << 7];
    #pragma unroll 8
    for (int i = 0; i < 32; ++i) {      // 32 broadcast ds_read_b128 = 128 g
        const float4 v = xs4[i];
        const float xg_[4] = { v.x, v.y, v.z, v.w };
        #pragma unroll
        for (int j = 0; j < 4; ++j) {
            const float xg = xg_[j];
            const v2f xg2 = { xg, xg };
            const v2f arg = __builtin_elementwise_fma(a2, xg2, bb); // v_pk_fma_f32
            const v2f e   = { EXP2(arg.x), EXP2(arg.y) };
            den += e;                                               // v_pk_add_f32
            num = __builtin_elementwise_fma(e, xg2, num);           // v_pk_fma_f32
        }
    }
    *(v2f*)&pden[sl][f0] = den;
    *(v2f*)&pnum[sl][f0] = num;
    __syncthreads();

    // Combine 4 slices per f, s_f = num/den, block-sum over 512 f's.
    float sf = 0.0f;
    if (tid < F_DIM) {
        float D = 0.0f, N = 0.0f;
        #pragma unroll
        for (int s = 0; s < 4; ++s) { D += pden[s][tid]; N += pnum[s][tid]; }
        sf = N / D;
    }
    float t = sf;
    for (int o = 32; o > 0; o >>= 1) t += __shfl_down(t, o);
    if (lane == 0 && wave < 8) wsum[wave] = t;
    __syncthreads();

    if (tid < 128) {
        float total = 0.0f;
        #pragma unroll
        for (int i = 0; i < 8; ++i) total += wsum[i];
        out[row * 128 + tid] = total * (1.0f / (float)F_DIM) * wv[tid];
    }
}

extern "C" void kernel_launch(void* const* d_in, const int* in_sizes, int n_in,
                              void* d_out, int out_size, void* d_ws, size_t ws_size,
                              hipStream_t stream) {
    const float* x  = (const float*)d_in[0];  // [8,32,512]
    const float* wq = (const float*)d_in[1];  // [1,128]
    const float* wk = (const float*)d_in[2];  // [1,128]
    const float* wv = (const float*)d_in[3];  // [1,128]
    float* out = (float*)d_out;               // [8,32,128]

    intravol_attn<<<256, 1024, 0, stream>>>(x, wq, wk, wv, out);
}